// Round 19
// baseline (136.305 us; speedup 1.0000x reference)
//
#include <hip/hip_runtime.h>
#include <hip/hip_bf16.h>

typedef unsigned short u16;
typedef __bf16 bf16x8 __attribute__((ext_vector_type(8)));
typedef float f32x4 __attribute__((ext_vector_type(4)));

#define QSCALE (0.125f * 1.44269504088896340736f)   // hd^-0.5 * log2(e), folded into Q

__device__ __forceinline__ u16 f2bf(float f) {
    __hip_bfloat16 h = __float2bfloat16(f);
    return __builtin_bit_cast(u16, h);
}
__device__ __forceinline__ float bf2f(u16 u) {
    unsigned int x = ((unsigned int)u) << 16;
    return __builtin_bit_cast(float, x);
}
__device__ __forceinline__ bf16x8 ld_bf8(const u16* p) {
    uint4 u = *reinterpret_cast<const uint4*>(p);
    return __builtin_bit_cast(bf16x8, u);
}
__device__ __forceinline__ bf16x8 pack8f(f32x4 a, f32x4 b) {
    union { bf16x8 v; u16 u[8]; } r;
    #pragma unroll
    for (int i = 0; i < 4; i++) { r.u[i] = f2bf(a[i]); r.u[4+i] = f2bf(b[i]); }
    return r.v;
}
__device__ __forceinline__ bf16x8 pack8u(ushort4 a, ushort4 b) {
    union { bf16x8 v; ushort4 u[2]; } r;
    r.u[0] = a; r.u[1] = b;
    return r.v;
}

#define GLOAD_LDS16(g, l) __builtin_amdgcn_global_load_lds( \
    (const __attribute__((address_space(1))) unsigned int*)(g), \
    (__attribute__((address_space(3))) unsigned int*)(l), 16, 0, 0)

// counted vmcnt wait (T4): N = VMEM ops allowed to stay in flight
template<int N> __device__ __forceinline__ void s_wait_vmcnt() {
    if constexpr (N == 0)       asm volatile("s_waitcnt vmcnt(0)" ::: "memory");
    else if constexpr (N == 3)  asm volatile("s_waitcnt vmcnt(3)" ::: "memory");
    else if constexpr (N == 4)  asm volatile("s_waitcnt vmcnt(4)" ::: "memory");
    else if constexpr (N == 8)  asm volatile("s_waitcnt vmcnt(8)" ::: "memory");
    else if constexpr (N == 14) asm volatile("s_waitcnt vmcnt(14)" ::: "memory");
}
__device__ __forceinline__ void s_bar() {
    __builtin_amdgcn_sched_barrier(0);
    __builtin_amdgcn_s_barrier();
    __builtin_amdgcn_sched_barrier(0);
}

// ---------------------------------------------------------------- prep ----
// f32->bf16 conversions; token-size weight tables (f32 for V-prescale,
// bf16 for the attn denominator fragment); zero the queue counter.
__global__ __launch_bounds__(256) void prep_kernel(
    const float* __restrict__ x, const float* __restrict__ qkvw,
    const float* __restrict__ projw, const float* __restrict__ ts,
    const unsigned char* __restrict__ kpm,
    u16* __restrict__ Xb, u16* __restrict__ Wq, u16* __restrict__ Wp,
    float* __restrict__ tsw, u16* __restrict__ tbf, int* __restrict__ qarr)
{
    int i = blockIdx.x * 256 + threadIdx.x;
    const int XC4 = 4096 * 768 / 4;
    const int WQ4 = 2304 * 768 / 4;
    const int WP4 = 768 * 768 / 4;
    const float* src = nullptr; u16* dst = nullptr;
    if (i < XC4) { src = x; dst = Xb; }
    else {
        i -= XC4;
        if (i < WQ4) { src = qkvw; dst = Wq; }
        else {
            i -= WQ4;
            if (i < WP4) { src = projw; dst = Wp; }
            else {
                i -= WP4;
                if (i < 1024) {
                    float4 t = *(const float4*)(ts + i*4);
                    uchar4 k = *(const uchar4*)(kpm + i*4);
                    float4 r;
                    r.x = k.x ? 0.f : fmaxf(t.x, 1e-8f);
                    r.y = k.y ? 0.f : fmaxf(t.y, 1e-8f);
                    r.z = k.z ? 0.f : fmaxf(t.z, 1e-8f);
                    r.w = k.w ? 0.f : fmaxf(t.w, 1e-8f);
                    *(float4*)(tsw + i*4) = r;
                    ushort4 o;
                    o.x = f2bf(r.x); o.y = f2bf(r.y);
                    o.z = f2bf(r.z); o.w = f2bf(r.w);
                    *(ushort4*)(tbf + i*4) = o;
                    return;
                }
                i -= 1024;
                if (i < 256) qarr[i] = 0;
                return;
            }
        }
    }
    float4 v = *(const float4*)(src + i*4);
    ushort4 o;
    o.x = f2bf(v.x); o.y = f2bf(v.y); o.z = f2bf(v.z); o.w = f2bf(v.w);
    *(ushort4*)(dst + i*4) = o;
}

// ---------------------------------------------------------------- GEMM ----
// C[m][n] = sum_k A[m][k]*Bm[n][k] (+bias). Tile = (MI*32) x 128, BK=32,
// 4 waves (2x2). 3-buffer, 1-ahead prefetch, ONE barrier + counted
// vmcnt(SA) per K-step (exact R13 configuration — best measured).
template<int EPI, int MI, int MINW>
__global__ __launch_bounds__(256, MINW) void gemm_bt(
    const u16* __restrict__ A, const u16* __restrict__ Bm,
    const float* __restrict__ bias, const float* __restrict__ tsw,
    u16* __restrict__ Qb, u16* __restrict__ Kb, u16* __restrict__ Vt,
    float* __restrict__ outp)
{
    constexpr int BM = MI * 32;
    constexpr int ACALLS = MI / 2;
    constexpr int SA = ACALLS + 2;       // stage calls per wave per iter
    constexpr int NT = 24;
    __shared__ u16 As[3][BM * 32];
    __shared__ u16 Bs[3][128 * 32];
    const int K = 768;
    const int tid = threadIdx.x;
    const int nwg = gridDim.x * gridDim.y;
    const int flat = blockIdx.y * gridDim.x + blockIdx.x;
    const int per = nwg >> 3;
    const int swz = (flat & 7) * per + (flat >> 3);
    const int m0 = (swz / gridDim.x) * BM;
    const int n0 = (swz % gridDim.x) * 128;
    const int w = tid >> 6, lane = tid & 63;
    const int wr = (w >> 1) * (MI * 16), wc = (w & 1) * 64;
    const int g = lane >> 4, l16 = lane & 15;

    const int srow = lane >> 2;
    const int scol = (lane & 3) * 8;
    const u16* gA[ACALLS];
    #pragma unroll
    for (int c = 0; c < ACALLS; c++)
        gA[c] = A + (size_t)(m0 + (c*4 + w)*16 + srow) * K + scol;
    const u16* gB[2];
    #pragma unroll
    for (int c = 0; c < 2; c++)
        gB[c] = Bm + (size_t)(n0 + (c*4 + w)*16 + srow) * K + scol;

#define GSTAGE(buf, kk) do { \
    _Pragma("unroll") \
    for (int c = 0; c < ACALLS; c++) \
        GLOAD_LDS16(gA[c] + (kk), &As[buf][(c*4 + w) * 512]); \
    _Pragma("unroll") \
    for (int c = 0; c < 2; c++) \
        GLOAD_LDS16(gB[c] + (kk), &Bs[buf][(c*4 + w) * 512]); } while (0)

    f32x4 acc[MI][4] = {};
    GSTAGE(0, 0);
    int cur = 0;
    for (int it = 0; it < NT; it++) {
        const int k0 = it * 32;
        const int nxt = (cur == 2) ? 0 : cur + 1;
        if (it + 1 < NT) {
            GSTAGE(nxt, k0 + 32);
            s_wait_vmcnt<SA>();          // stage(it) done; stage(it+1) flies on
        } else {
            s_wait_vmcnt<0>();
        }
        s_bar();                         // buf[cur] present for all waves
        bf16x8 af[MI], bfr[4];
        #pragma unroll
        for (int i = 0; i < MI; i++) af[i]  = ld_bf8(&As[cur][(wr + i*16 + l16)*32 + g*8]);
        #pragma unroll
        for (int j = 0; j < 4; j++)  bfr[j] = ld_bf8(&Bs[cur][(wc + j*16 + l16)*32 + g*8]);
        #pragma unroll
        for (int i = 0; i < MI; i++)
            #pragma unroll
            for (int j = 0; j < 4; j++)
                acc[i][j] = __builtin_amdgcn_mfma_f32_16x16x32_bf16(af[i], bfr[j], acc[i][j], 0, 0, 0);
        cur = nxt;
        // no second barrier: buf reuse distance = 2 barriers (safe)
    }
#undef GSTAGE

    #pragma unroll
    for (int j = 0; j < 4; j++) {
        const int n = n0 + wc + j*16 + l16;
        const float bs = bias[n];
        #pragma unroll
        for (int i = 0; i < MI; i++) {
            #pragma unroll
            for (int r = 0; r < 4; r++) {
                const int m = m0 + wr + i*16 + g*4 + r;
                float v = acc[i][j][r] + bs;
                if (EPI == 0) {
                    int b = m >> 11, l = m & 2047;
                    unsigned int which = (unsigned int)n / 768u;
                    int rem = n - (int)which * 768;
                    int h = rem >> 6, d = rem & 63;
                    int bh = b * 12 + h;
                    if (which == 0)      Qb[((size_t)bh*2048 + l)*64 + d] = f2bf(v * QSCALE);
                    else if (which == 1) Kb[((size_t)bh*2048 + l)*64 + d] = f2bf(v);
                    else                 Vt[((size_t)bh*64 + d)*2048 + l] = f2bf(v * tsw[b*2048 + l]);
                } else {
                    outp[(size_t)m * 768 + n] = v;
                }
            }
        }
    }
}

// ----------------------------------------------------------- attention ----
// Persistent-block flash attention, swapped-operand form. NEW: K and t are
// PREFETCHED TO REGISTERS one tile ahead (coalesced 16B/lane loads) — QK^T
// starts immediately after the barrier with zero LDS latency; only V is
// LDS-staged (3-buffer, pre-barrier, R13-proven). Steady wait vmcnt(14) =
// {4 t + 8 K + 2 V-stage} of tile kt+1 in flight. Grid 512, (256,2).
__global__ __launch_bounds__(256, 2) void attn_kernel(
    const u16* __restrict__ Q, const u16* __restrict__ Kb,
    const u16* __restrict__ Vt, const u16* __restrict__ tbf,
    u16* __restrict__ O, int* __restrict__ qarr)
{
    __shared__ u16 Vs[3][64 * 64];
    __shared__ int s_item;
    const int tid = threadIdx.x;
    const int w = tid >> 6, lane = tid & 63;
    const int g = lane >> 4, l16 = lane & 15;
    const int sw = l16 & 7;
    const int srow = lane >> 3;
    const int sslot = (lane & 7) ^ srow;

    for (;;) {
        __syncthreads();                            // s_item rewrite guard
        if (tid == 0) {
            const int i = atomicAdd(&qarr[0], 1);
            s_item = (i < 768) ? i : -1;
        }
        __syncthreads();
        const int item = s_item;
        if (item < 0) return;
        const int qt = 31 - (item / 24);            // largest work first
        const int bh = item - (item / 24) * 24;
        const int b = bh / 12, h = bh - b * 12;
        const int q0 = qt * 64 + w * 16;            // this wave's 16 q-rows
        const int nkt = qt + 1;

        const u16* Qp = Q + ((size_t)bh * 2048 + q0) * 64;
        const u16* Kp = Kb + (size_t)bh * 2048 * 64;
        const u16* Vp = Vt + (size_t)bh * 64 * 2048;
        const u16* tb = tbf + b * 2048;

        const u16* gV0 = Vp + (size_t)(w*16 +     srow) * 2048 + sslot * 8;
        const u16* gV1 = Vp + (size_t)(w*16 + 8 + srow) * 2048 + sslot * 8;

#define VSTAGE(buf, kk) do { \
    GLOAD_LDS16(gV0 + (kk), &Vs[buf][(w*16    ) * 64]); \
    GLOAD_LDS16(gV1 + (kk), &Vs[buf][(w*16 + 8) * 64]); } while (0)

        const bf16x8 qf0 = ld_bf8(Qp + l16 * 64 + g * 8);
        const bf16x8 qf1 = ld_bf8(Qp + l16 * 64 + 32 + g * 8);

        // prologue: t(0) + K(0) fragments to regs, V(0) staged
        ushort4 tc0, tc1, tc2, tc3;
        { const u16* tp = tb + 4*g;
          tc0 = *(const ushort4*)(tp);      tc1 = *(const ushort4*)(tp + 16);
          tc2 = *(const ushort4*)(tp + 32); tc3 = *(const ushort4*)(tp + 48); }
        bf16x8 kfc[4][2];
        #pragma unroll
        for (int t = 0; t < 4; t++) {
            const u16* kp = Kp + (size_t)(t*16 + l16) * 64 + g * 8;
            kfc[t][0] = ld_bf8(kp);
            kfc[t][1] = ld_bf8(kp + 32);
        }
        VSTAGE(0, 0);

        f32x4 o[4] = {};
        f32x4 lpacc = {};
        float m = -1e30f;
        const int qmy = q0 + l16;                   // q-row this lane reduces

        int cur = 0;
        for (int kt = 0; kt < nkt; kt++) {
            const int k0 = kt * 64;
            const int nxt = (cur == 2) ? 0 : cur + 1;

            ushort4 tn0 = tc0, tn1 = tc1, tn2 = tc2, tn3 = tc3;
            bf16x8 kfn[4][2];
            if (kt + 1 < nkt) {                     // block-uniform
                const u16* tp = tb + k0 + 64 + 4*g;
                tn0 = *(const ushort4*)(tp);      tn1 = *(const ushort4*)(tp + 16);
                tn2 = *(const ushort4*)(tp + 32); tn3 = *(const ushort4*)(tp + 48);
                #pragma unroll
                for (int t = 0; t < 4; t++) {
                    const u16* kp = Kp + (size_t)(k0 + 64 + t*16 + l16) * 64 + g * 8;
                    kfn[t][0] = ld_bf8(kp);
                    kfn[t][1] = ld_bf8(kp + 32);
                }
                VSTAGE(nxt, k0 + 64);
                s_wait_vmcnt<14>();                 // tile-kt loads done; 14 newest fly
            } else {
                s_wait_vmcnt<0>();
            }
            s_bar();                                // Vs[cur] present for all waves

            // ---- V LDS reads (overlap QK + softmax) ----
            const int gh = g >> 1, gl = 4 * (g & 1);
            ushort4 va[4][4];
            #pragma unroll
            for (int j = 0; j < 4; j++) {
                const u16* vb = &Vs[cur][(j*16 + l16) * 64];
                va[j][0] = *(const ushort4*)(vb + (((0 + gh) ^ sw) << 3) + gl);
                va[j][1] = *(const ushort4*)(vb + (((2 + gh) ^ sw) << 3) + gl);
                va[j][2] = *(const ushort4*)(vb + (((4 + gh) ^ sw) << 3) + gl);
                va[j][3] = *(const ushort4*)(vb + (((6 + gh) ^ sw) << 3) + gl);
            }

            // ---- S^T = K · Q^T (K already in registers!) ----
            f32x4 s[4];
            #pragma unroll
            for (int t = 0; t < 4; t++) {
                f32x4 z = {};
                z = __builtin_amdgcn_mfma_f32_16x16x32_bf16(kfc[t][0], qf0, z, 0, 0, 0);
                z = __builtin_amdgcn_mfma_f32_16x16x32_bf16(kfc[t][1], qf1, z, 0, 0, 0);
                s[t] = z;
            }
            // ---- causal mask only on the diagonal tile (block-uniform) ----
            if (kt == qt) {
                #pragma unroll
                for (int t = 0; t < 4; t++)
                    #pragma unroll
                    for (int r = 0; r < 4; r++) {
                        const int key = k0 + t*16 + 4*g + r;
                        if (key > qmy) s[t][r] = -1e30f;
                    }
            }
            // ---- per-q max ----
            float pmax = -1e30f;
            #pragma unroll
            for (int t = 0; t < 4; t++)
                #pragma unroll
                for (int r = 0; r < 4; r++)
                    pmax = fmaxf(pmax, s[t][r]);
            pmax = fmaxf(pmax, __shfl_xor(pmax, 16));
            pmax = fmaxf(pmax, __shfl_xor(pmax, 32));
            // ---- online update, defer-max (THR=8, log2 domain) ----
            if (!__all(pmax <= m + 8.f)) {
                const float mn = fmaxf(m, pmax);
                const float sc = __builtin_amdgcn_exp2f(m - mn);
                m = mn;
                #pragma unroll
                for (int r = 0; r < 4; r++) {
                    const float scr = __shfl(sc, (lane & 48) + 4*g + r);
                    o[0][r] *= scr; o[1][r] *= scr; o[2][r] *= scr; o[3][r] *= scr;
                    lpacc[r] *= scr;
                }
            }
            // ---- P = exp2(s - m) ----
            #pragma unroll
            for (int t = 0; t < 4; t++)
                #pragma unroll
                for (int r = 0; r < 4; r++)
                    s[t][r] = __builtin_amdgcn_exp2f(s[t][r] - m);
            const bf16x8 pa01 = pack8f(s[0], s[1]);
            const bf16x8 pa23 = pack8f(s[2], s[3]);
            __builtin_amdgcn_s_setprio(1);
            // ---- denominator: Σ p·t via MFMA with t-fragment B ----
            lpacc = __builtin_amdgcn_mfma_f32_16x16x32_bf16(pa01, pack8u(tc0, tc1), lpacc, 0, 0, 0);
            lpacc = __builtin_amdgcn_mfma_f32_16x16x32_bf16(pa23, pack8u(tc2, tc3), lpacc, 0, 0, 0);
            // ---- O += P·V' (V prescaled by t; key-perm cancels A vs B) ----
            #pragma unroll
            for (int j = 0; j < 4; j++) {
                o[j] = __builtin_amdgcn_mfma_f32_16x16x32_bf16(pa01, pack8u(va[j][0], va[j][1]), o[j], 0, 0, 0);
                o[j] = __builtin_amdgcn_mfma_f32_16x16x32_bf16(pa23, pack8u(va[j][2], va[j][3]), o[j], 0, 0, 0);
            }
            __builtin_amdgcn_s_setprio(0);
            if (kt + 1 < nkt) {                     // rotate prefetched regs
                tc0 = tn0; tc1 = tn1; tc2 = tn2; tc3 = tn3;
                #pragma unroll
                for (int t = 0; t < 4; t++) {
                    kfc[t][0] = kfn[t][0];
                    kfc[t][1] = kfn[t][1];
                }
            }
            cur = nxt;
        }
#undef VSTAGE

        // ---- normalize + write (lpacc[r] = Σ p·t for q-row 4g+r) ----
        float rlr[4];
        #pragma unroll
        for (int r = 0; r < 4; r++) rlr[r] = 1.f / lpacc[r];
        #pragma unroll
        for (int j = 0; j < 4; j++)
            #pragma unroll
            for (int r = 0; r < 4; r++) {
                const int q = q0 + 4*g + r;
                O[((size_t)b*2048 + q)*768 + h*64 + j*16 + l16] = f2bf(o[j][r] * rlr[r]);
            }
    }
}

// ------------------------------------------------------------- k_merge ----
__global__ __launch_bounds__(256) void kmerge_kernel(
    const u16* __restrict__ Kb, float* __restrict__ out)
{
    const int idx = blockIdx.x * 256 + threadIdx.x;   // < 2*2048*16
    const int d4 = (idx & 15) * 4;
    const int l = (idx >> 4) & 2047;
    const int b = idx >> 15;
    float4 acc = {0.f, 0.f, 0.f, 0.f};
    #pragma unroll
    for (int h = 0; h < 12; h++) {
        ushort4 v = *(const ushort4*)&Kb[(((size_t)(b*12 + h))*2048 + l)*64 + d4];
        acc.x += bf2f(v.x); acc.y += bf2f(v.y);
        acc.z += bf2f(v.z); acc.w += bf2f(v.w);
    }
    const float s = 1.f / 12.f;
    float4 r = {acc.x * s, acc.y * s, acc.z * s, acc.w * s};
    *(float4*)&out[(((size_t)b*2048 + l))*64 + d4] = r;
}

// -------------------------------------------------------------- launch ----
extern "C" void kernel_launch(void* const* d_in, const int* in_sizes, int n_in,
                              void* d_out, int out_size, void* d_ws, size_t ws_size,
                              hipStream_t stream)
{
    const float* x     = (const float*)d_in[0];
    const float* ts    = (const float*)d_in[1];
    // d_in[2] = attn_mask (causal, hardcoded)
    const unsigned char* kpm = (const unsigned char*)d_in[3];
    const float* qkvw  = (const float*)d_in[4];
    const float* qkvb  = (const float*)d_in[5];
    const float* projw = (const float*)d_in[6];
    const float* projb = (const float*)d_in[7];
    float* out = (float*)d_out;

    char* ws = (char*)d_ws;
    u16* Xb = (u16*)ws;  ws += (size_t)4096 * 768 * 2;
    u16* Wq = (u16*)ws;  ws += (size_t)2304 * 768 * 2;
    u16* Wp = (u16*)ws;  ws += (size_t)768 * 768 * 2;
    u16* Qb = (u16*)ws;  ws += (size_t)24 * 2048 * 64 * 2;
    u16* Kb = (u16*)ws;  ws += (size_t)24 * 2048 * 64 * 2;
    u16* Vt = (u16*)ws;  ws += (size_t)24 * 2048 * 64 * 2;
    u16* Ob = (u16*)ws;  ws += (size_t)4096 * 768 * 2;
    float* tsw = (float*)ws;  ws += (size_t)2 * 2048 * 4;
    u16* tbf = (u16*)ws;  ws += (size_t)2 * 2048 * 2;
    int* qarr = (int*)ws;

    const int prep4 = (4096*768 + 2304*768 + 768*768) / 4 + 1024 + 256;
    prep_kernel<<<(prep4 + 255) / 256, 256, 0, stream>>>(
        x, qkvw, projw, ts, kpm, Xb, Wq, Wp, tsw, tbf, qarr);

    gemm_bt<0, 4, 2><<<dim3(18, 32), 256, 0, stream>>>(Xb, Wq, qkvb, tsw, Qb, Kb, Vt, nullptr);

    attn_kernel<<<dim3(512), 256, 0, stream>>>(Qb, Kb, Vt, tbf, Ob, qarr);

    kmerge_kernel<<<(2*2048*16) / 256, 256, 0, stream>>>(Kb, out + 3145728);

    gemm_bt<1, 2, 2><<<dim3(6, 64), 256, 0, stream>>>(Ob, Wp, projb, nullptr, nullptr, nullptr, nullptr, out);
}

// Round 20
// 112.784 us; speedup vs baseline: 1.2085x; 1.2085x over previous
//
#include <hip/hip_runtime.h>
#include <hip/hip_bf16.h>

typedef unsigned short u16;
typedef __bf16 bf16x8 __attribute__((ext_vector_type(8)));
typedef float f32x4 __attribute__((ext_vector_type(4)));

#define QSCALE (0.125f * 1.44269504088896340736f)   // hd^-0.5 * log2(e), folded into Q

__device__ __forceinline__ u16 f2bf(float f) {
    __hip_bfloat16 h = __float2bfloat16(f);
    return __builtin_bit_cast(u16, h);
}
__device__ __forceinline__ float bf2f(u16 u) {
    unsigned int x = ((unsigned int)u) << 16;
    return __builtin_bit_cast(float, x);
}
__device__ __forceinline__ bf16x8 ld_bf8(const u16* p) {
    uint4 u = *reinterpret_cast<const uint4*>(p);
    return __builtin_bit_cast(bf16x8, u);
}
__device__ __forceinline__ bf16x8 pack8f(f32x4 a, f32x4 b) {
    union { bf16x8 v; u16 u[8]; } r;
    #pragma unroll
    for (int i = 0; i < 4; i++) { r.u[i] = f2bf(a[i]); r.u[4+i] = f2bf(b[i]); }
    return r.v;
}
__device__ __forceinline__ bf16x8 pack8u(ushort4 a, ushort4 b) {
    union { bf16x8 v; ushort4 u[2]; } r;
    r.u[0] = a; r.u[1] = b;
    return r.v;
}

#define GLOAD_LDS16(g, l) __builtin_amdgcn_global_load_lds( \
    (const __attribute__((address_space(1))) unsigned int*)(g), \
    (__attribute__((address_space(3))) unsigned int*)(l), 16, 0, 0)

// counted vmcnt wait (T4): N = VMEM ops allowed to stay in flight
template<int N> __device__ __forceinline__ void s_wait_vmcnt() {
    if constexpr (N == 0)       asm volatile("s_waitcnt vmcnt(0)" ::: "memory");
    else if constexpr (N == 3)  asm volatile("s_waitcnt vmcnt(3)" ::: "memory");
    else if constexpr (N == 4)  asm volatile("s_waitcnt vmcnt(4)" ::: "memory");
    else if constexpr (N == 8)  asm volatile("s_waitcnt vmcnt(8)" ::: "memory");
}
__device__ __forceinline__ void s_bar() {
    __builtin_amdgcn_sched_barrier(0);
    __builtin_amdgcn_s_barrier();
    __builtin_amdgcn_sched_barrier(0);
}

// ---------------------------------------------------------------- prep ----
// f32->bf16 conversions; token-size weight tables (f32 for V-prescale,
// bf16 for the attn denominator fragment); zero the queue counter.
__global__ __launch_bounds__(256) void prep_kernel(
    const float* __restrict__ x, const float* __restrict__ qkvw,
    const float* __restrict__ projw, const float* __restrict__ ts,
    const unsigned char* __restrict__ kpm,
    u16* __restrict__ Xb, u16* __restrict__ Wq, u16* __restrict__ Wp,
    float* __restrict__ tsw, u16* __restrict__ tbf, int* __restrict__ qarr)
{
    int i = blockIdx.x * 256 + threadIdx.x;
    const int XC4 = 4096 * 768 / 4;
    const int WQ4 = 2304 * 768 / 4;
    const int WP4 = 768 * 768 / 4;
    const float* src = nullptr; u16* dst = nullptr;
    if (i < XC4) { src = x; dst = Xb; }
    else {
        i -= XC4;
        if (i < WQ4) { src = qkvw; dst = Wq; }
        else {
            i -= WQ4;
            if (i < WP4) { src = projw; dst = Wp; }
            else {
                i -= WP4;
                if (i < 1024) {
                    float4 t = *(const float4*)(ts + i*4);
                    uchar4 k = *(const uchar4*)(kpm + i*4);
                    float4 r;
                    r.x = k.x ? 0.f : fmaxf(t.x, 1e-8f);
                    r.y = k.y ? 0.f : fmaxf(t.y, 1e-8f);
                    r.z = k.z ? 0.f : fmaxf(t.z, 1e-8f);
                    r.w = k.w ? 0.f : fmaxf(t.w, 1e-8f);
                    *(float4*)(tsw + i*4) = r;
                    ushort4 o;
                    o.x = f2bf(r.x); o.y = f2bf(r.y);
                    o.z = f2bf(r.z); o.w = f2bf(r.w);
                    *(ushort4*)(tbf + i*4) = o;
                    return;
                }
                i -= 1024;
                if (i < 256) qarr[i] = 0;
                return;
            }
        }
    }
    float4 v = *(const float4*)(src + i*4);
    ushort4 o;
    o.x = f2bf(v.x); o.y = f2bf(v.y); o.z = f2bf(v.z); o.w = f2bf(v.w);
    *(ushort4*)(dst + i*4) = o;
}

// ---------------------------------------------------------------- GEMM ----
// C[m][n] = sum_k A[m][k]*Bm[n][k] (+bias). Tile = (MI*32) x 128, BK=32,
// 4 waves (2x2). 3-buffer, 1-ahead prefetch, ONE barrier + counted
// vmcnt(SA) per K-step (exact R13 configuration — best measured).
template<int EPI, int MI, int MINW>
__global__ __launch_bounds__(256, MINW) void gemm_bt(
    const u16* __restrict__ A, const u16* __restrict__ Bm,
    const float* __restrict__ bias, const float* __restrict__ tsw,
    u16* __restrict__ Qb, u16* __restrict__ Kb, u16* __restrict__ Vt,
    float* __restrict__ outp)
{
    constexpr int BM = MI * 32;
    constexpr int ACALLS = MI / 2;
    constexpr int SA = ACALLS + 2;       // stage calls per wave per iter
    constexpr int NT = 24;
    __shared__ u16 As[3][BM * 32];
    __shared__ u16 Bs[3][128 * 32];
    const int K = 768;
    const int tid = threadIdx.x;
    const int nwg = gridDim.x * gridDim.y;
    const int flat = blockIdx.y * gridDim.x + blockIdx.x;
    const int per = nwg >> 3;
    const int swz = (flat & 7) * per + (flat >> 3);
    const int m0 = (swz / gridDim.x) * BM;
    const int n0 = (swz % gridDim.x) * 128;
    const int w = tid >> 6, lane = tid & 63;
    const int wr = (w >> 1) * (MI * 16), wc = (w & 1) * 64;
    const int g = lane >> 4, l16 = lane & 15;

    const int srow = lane >> 2;
    const int scol = (lane & 3) * 8;
    const u16* gA[ACALLS];
    #pragma unroll
    for (int c = 0; c < ACALLS; c++)
        gA[c] = A + (size_t)(m0 + (c*4 + w)*16 + srow) * K + scol;
    const u16* gB[2];
    #pragma unroll
    for (int c = 0; c < 2; c++)
        gB[c] = Bm + (size_t)(n0 + (c*4 + w)*16 + srow) * K + scol;

#define GSTAGE(buf, kk) do { \
    _Pragma("unroll") \
    for (int c = 0; c < ACALLS; c++) \
        GLOAD_LDS16(gA[c] + (kk), &As[buf][(c*4 + w) * 512]); \
    _Pragma("unroll") \
    for (int c = 0; c < 2; c++) \
        GLOAD_LDS16(gB[c] + (kk), &Bs[buf][(c*4 + w) * 512]); } while (0)

    f32x4 acc[MI][4] = {};
    GSTAGE(0, 0);
    int cur = 0;
    for (int it = 0; it < NT; it++) {
        const int k0 = it * 32;
        const int nxt = (cur == 2) ? 0 : cur + 1;
        if (it + 1 < NT) {
            GSTAGE(nxt, k0 + 32);
            s_wait_vmcnt<SA>();          // stage(it) done; stage(it+1) flies on
        } else {
            s_wait_vmcnt<0>();
        }
        s_bar();                         // buf[cur] present for all waves
        bf16x8 af[MI], bfr[4];
        #pragma unroll
        for (int i = 0; i < MI; i++) af[i]  = ld_bf8(&As[cur][(wr + i*16 + l16)*32 + g*8]);
        #pragma unroll
        for (int j = 0; j < 4; j++)  bfr[j] = ld_bf8(&Bs[cur][(wc + j*16 + l16)*32 + g*8]);
        #pragma unroll
        for (int i = 0; i < MI; i++)
            #pragma unroll
            for (int j = 0; j < 4; j++)
                acc[i][j] = __builtin_amdgcn_mfma_f32_16x16x32_bf16(af[i], bfr[j], acc[i][j], 0, 0, 0);
        cur = nxt;
        // no second barrier: buf reuse distance = 2 barriers (safe)
    }
#undef GSTAGE

    #pragma unroll
    for (int j = 0; j < 4; j++) {
        const int n = n0 + wc + j*16 + l16;
        const float bs = bias[n];
        #pragma unroll
        for (int i = 0; i < MI; i++) {
            #pragma unroll
            for (int r = 0; r < 4; r++) {
                const int m = m0 + wr + i*16 + g*4 + r;
                float v = acc[i][j][r] + bs;
                if (EPI == 0) {
                    int b = m >> 11, l = m & 2047;
                    unsigned int which = (unsigned int)n / 768u;
                    int rem = n - (int)which * 768;
                    int h = rem >> 6, d = rem & 63;
                    int bh = b * 12 + h;
                    if (which == 0)      Qb[((size_t)bh*2048 + l)*64 + d] = f2bf(v * QSCALE);
                    else if (which == 1) Kb[((size_t)bh*2048 + l)*64 + d] = f2bf(v);
                    else                 Vt[((size_t)bh*64 + d)*2048 + l] = f2bf(v * tsw[b*2048 + l]);
                } else {
                    outp[(size_t)m * 768 + n] = v;
                }
            }
        }
    }
}

// ----------------------------------------------------------- attention ----
// Persistent-block flash attention, swapped-operand form (R13 loop body).
// TWO LDS buffers (32.5KB) with staging issued AFTER the barrier (race-free:
// at bar(kt) all waves' reads of buf(kt-1) are done; stage(kt+1) targets
// exactly buf(kt-1)). (256,2) — NO min-wave forcing (R18's spill cause);
// actual residency governed by LDS 32.5KB -> up to 4 blocks/CU. Grid 1024.
__global__ __launch_bounds__(256, 2) void attn_kernel(
    const u16* __restrict__ Q, const u16* __restrict__ Kb,
    const u16* __restrict__ Vt, const u16* __restrict__ tbf,
    u16* __restrict__ O, int* __restrict__ qarr)
{
    __shared__ u16 Ks[2][64 * 64];
    __shared__ u16 Vs[2][64 * 64];
    __shared__ int s_item;
    const int tid = threadIdx.x;
    const int w = tid >> 6, lane = tid & 63;
    const int g = lane >> 4, l16 = lane & 15;
    const int sw = l16 & 7;
    const int srow = lane >> 3;
    const int sslot = (lane & 7) ^ srow;

    for (;;) {
        __syncthreads();                            // s_item rewrite guard
        if (tid == 0) {
            const int i = atomicAdd(&qarr[0], 1);
            s_item = (i < 768) ? i : -1;
        }
        __syncthreads();
        const int item = s_item;
        if (item < 0) return;
        const int qt = 31 - (item / 24);            // largest work first
        const int bh = item - (item / 24) * 24;
        const int b = bh / 12, h = bh - b * 12;
        const int q0 = qt * 64 + w * 16;            // this wave's 16 q-rows
        const int nkt = qt + 1;

        const u16* Qp = Q + ((size_t)bh * 2048 + q0) * 64;
        const u16* Kp = Kb + (size_t)bh * 2048 * 64;
        const u16* Vp = Vt + (size_t)bh * 64 * 2048;
        const u16* tb = tbf + b * 2048;

        const u16* gK0 = Kp + (size_t)(w*16 +     srow) * 64   + sslot * 8;
        const u16* gK1 = Kp + (size_t)(w*16 + 8 + srow) * 64   + sslot * 8;
        const u16* gV0 = Vp + (size_t)(w*16 +     srow) * 2048 + sslot * 8;
        const u16* gV1 = Vp + (size_t)(w*16 + 8 + srow) * 2048 + sslot * 8;

#define ASTAGE(buf, kk) do { \
    GLOAD_LDS16(gK0 + (size_t)(kk) * 64, &Ks[buf][(w*16    ) * 64]); \
    GLOAD_LDS16(gK1 + (size_t)(kk) * 64, &Ks[buf][(w*16 + 8) * 64]); \
    GLOAD_LDS16(gV0 + (kk),              &Vs[buf][(w*16    ) * 64]); \
    GLOAD_LDS16(gV1 + (kk),              &Vs[buf][(w*16 + 8) * 64]); } while (0)

        const bf16x8 qf0 = ld_bf8(Qp + l16 * 64 + g * 8);
        const bf16x8 qf1 = ld_bf8(Qp + l16 * 64 + 32 + g * 8);

        // prologue: t(0) fragment + stage(0)
        ushort4 tc0, tc1, tc2, tc3;
        { const u16* tp = tb + 4*g;
          tc0 = *(const ushort4*)(tp);      tc1 = *(const ushort4*)(tp + 16);
          tc2 = *(const ushort4*)(tp + 32); tc3 = *(const ushort4*)(tp + 48); }
        ASTAGE(0, 0);

        f32x4 o[4] = {};
        f32x4 lpacc = {};
        float m = -1e30f;
        const int qmy = q0 + l16;                   // q-row this lane reduces

        for (int kt = 0; kt < nkt; kt++) {
            const int cur = kt & 1;
            const int k0 = kt * 64;

            ushort4 tn0 = tc0, tn1 = tc1, tn2 = tc2, tn3 = tc3;
            if (kt + 1 < nkt) {                     // block-uniform
                const u16* tp = tb + k0 + 64 + 4*g;
                tn0 = *(const ushort4*)(tp);      tn1 = *(const ushort4*)(tp + 16);
                tn2 = *(const ushort4*)(tp + 32); tn3 = *(const ushort4*)(tp + 48);
                s_wait_vmcnt<4>();                  // stage(kt) done; t(kt+1) flies on
            } else {
                s_wait_vmcnt<0>();
            }
            s_bar();                                // buf[cur] present; buf(kt-1) reads done
            if (kt + 1 < nkt)
                ASTAGE(cur ^ 1, k0 + 64);           // post-barrier stage (race-free)

            // ---- batch-issue ALL LDS reads (8 K b128 + 16 V b64) ----
            const int ko0 = 8 * (g ^ sw);
            bf16x8 kf[4][2];
            #pragma unroll
            for (int t = 0; t < 4; t++) {
                const u16* kb = &Ks[cur][(t*16 + l16) * 64];
                kf[t][0] = ld_bf8(kb + ko0);
                kf[t][1] = ld_bf8(kb + (ko0 ^ 32));
            }
            const int gh = g >> 1, gl = 4 * (g & 1);
            ushort4 va[4][4];
            #pragma unroll
            for (int j = 0; j < 4; j++) {
                const u16* vb = &Vs[cur][(j*16 + l16) * 64];
                va[j][0] = *(const ushort4*)(vb + (((0 + gh) ^ sw) << 3) + gl);
                va[j][1] = *(const ushort4*)(vb + (((2 + gh) ^ sw) << 3) + gl);
                va[j][2] = *(const ushort4*)(vb + (((4 + gh) ^ sw) << 3) + gl);
                va[j][3] = *(const ushort4*)(vb + (((6 + gh) ^ sw) << 3) + gl);
            }

            // ---- S^T = K · Q^T ----
            f32x4 s[4];
            #pragma unroll
            for (int t = 0; t < 4; t++) {
                f32x4 z = {};
                z = __builtin_amdgcn_mfma_f32_16x16x32_bf16(kf[t][0], qf0, z, 0, 0, 0);
                z = __builtin_amdgcn_mfma_f32_16x16x32_bf16(kf[t][1], qf1, z, 0, 0, 0);
                s[t] = z;
            }
            // ---- causal mask only on the diagonal tile (block-uniform) ----
            if (kt == qt) {
                #pragma unroll
                for (int t = 0; t < 4; t++)
                    #pragma unroll
                    for (int r = 0; r < 4; r++) {
                        const int key = k0 + t*16 + 4*g + r;
                        if (key > qmy) s[t][r] = -1e30f;
                    }
            }
            // ---- per-q max ----
            float pmax = -1e30f;
            #pragma unroll
            for (int t = 0; t < 4; t++)
                #pragma unroll
                for (int r = 0; r < 4; r++)
                    pmax = fmaxf(pmax, s[t][r]);
            pmax = fmaxf(pmax, __shfl_xor(pmax, 16));
            pmax = fmaxf(pmax, __shfl_xor(pmax, 32));
            // ---- online update, defer-max (THR=8, log2 domain) ----
            if (!__all(pmax <= m + 8.f)) {
                const float mn = fmaxf(m, pmax);
                const float sc = __builtin_amdgcn_exp2f(m - mn);
                m = mn;
                #pragma unroll
                for (int r = 0; r < 4; r++) {
                    const float scr = __shfl(sc, (lane & 48) + 4*g + r);
                    o[0][r] *= scr; o[1][r] *= scr; o[2][r] *= scr; o[3][r] *= scr;
                    lpacc[r] *= scr;
                }
            }
            // ---- P = exp2(s - m) ----
            #pragma unroll
            for (int t = 0; t < 4; t++)
                #pragma unroll
                for (int r = 0; r < 4; r++)
                    s[t][r] = __builtin_amdgcn_exp2f(s[t][r] - m);
            const bf16x8 pa01 = pack8f(s[0], s[1]);
            const bf16x8 pa23 = pack8f(s[2], s[3]);
            __builtin_amdgcn_s_setprio(1);
            // ---- denominator: Σ p·t via MFMA with t-fragment B ----
            lpacc = __builtin_amdgcn_mfma_f32_16x16x32_bf16(pa01, pack8u(tc0, tc1), lpacc, 0, 0, 0);
            lpacc = __builtin_amdgcn_mfma_f32_16x16x32_bf16(pa23, pack8u(tc2, tc3), lpacc, 0, 0, 0);
            // ---- O += P·V' (V prescaled by t; key-perm cancels A vs B) ----
            #pragma unroll
            for (int j = 0; j < 4; j++) {
                o[j] = __builtin_amdgcn_mfma_f32_16x16x32_bf16(pa01, pack8u(va[j][0], va[j][1]), o[j], 0, 0, 0);
                o[j] = __builtin_amdgcn_mfma_f32_16x16x32_bf16(pa23, pack8u(va[j][2], va[j][3]), o[j], 0, 0, 0);
            }
            __builtin_amdgcn_s_setprio(0);
            tc0 = tn0; tc1 = tn1; tc2 = tn2; tc3 = tn3;
        }
#undef ASTAGE

        // ---- normalize + write (lpacc[r] = Σ p·t for q-row 4g+r) ----
        float rlr[4];
        #pragma unroll
        for (int r = 0; r < 4; r++) rlr[r] = 1.f / lpacc[r];
        #pragma unroll
        for (int j = 0; j < 4; j++)
            #pragma unroll
            for (int r = 0; r < 4; r++) {
                const int q = q0 + 4*g + r;
                O[((size_t)b*2048 + q)*768 + h*64 + j*16 + l16] = f2bf(o[j][r] * rlr[r]);
            }
    }
}

// ------------------------------------------------------------- k_merge ----
__global__ __launch_bounds__(256) void kmerge_kernel(
    const u16* __restrict__ Kb, float* __restrict__ out)
{
    const int idx = blockIdx.x * 256 + threadIdx.x;   // < 2*2048*16
    const int d4 = (idx & 15) * 4;
    const int l = (idx >> 4) & 2047;
    const int b = idx >> 15;
    float4 acc = {0.f, 0.f, 0.f, 0.f};
    #pragma unroll
    for (int h = 0; h < 12; h++) {
        ushort4 v = *(const ushort4*)&Kb[(((size_t)(b*12 + h))*2048 + l)*64 + d4];
        acc.x += bf2f(v.x); acc.y += bf2f(v.y);
        acc.z += bf2f(v.z); acc.w += bf2f(v.w);
    }
    const float s = 1.f / 12.f;
    float4 r = {acc.x * s, acc.y * s, acc.z * s, acc.w * s};
    *(float4*)&out[(((size_t)b*2048 + l))*64 + d4] = r;
}

// -------------------------------------------------------------- launch ----
extern "C" void kernel_launch(void* const* d_in, const int* in_sizes, int n_in,
                              void* d_out, int out_size, void* d_ws, size_t ws_size,
                              hipStream_t stream)
{
    const float* x     = (const float*)d_in[0];
    const float* ts    = (const float*)d_in[1];
    // d_in[2] = attn_mask (causal, hardcoded)
    const unsigned char* kpm = (const unsigned char*)d_in[3];
    const float* qkvw  = (const float*)d_in[4];
    const float* qkvb  = (const float*)d_in[5];
    const float* projw = (const float*)d_in[6];
    const float* projb = (const float*)d_in[7];
    float* out = (float*)d_out;

    char* ws = (char*)d_ws;
    u16* Xb = (u16*)ws;  ws += (size_t)4096 * 768 * 2;
    u16* Wq = (u16*)ws;  ws += (size_t)2304 * 768 * 2;
    u16* Wp = (u16*)ws;  ws += (size_t)768 * 768 * 2;
    u16* Qb = (u16*)ws;  ws += (size_t)24 * 2048 * 64 * 2;
    u16* Kb = (u16*)ws;  ws += (size_t)24 * 2048 * 64 * 2;
    u16* Vt = (u16*)ws;  ws += (size_t)24 * 2048 * 64 * 2;
    u16* Ob = (u16*)ws;  ws += (size_t)4096 * 768 * 2;
    float* tsw = (float*)ws;  ws += (size_t)2 * 2048 * 4;
    u16* tbf = (u16*)ws;  ws += (size_t)2 * 2048 * 2;
    int* qarr = (int*)ws;

    const int prep4 = (4096*768 + 2304*768 + 768*768) / 4 + 1024 + 256;
    prep_kernel<<<(prep4 + 255) / 256, 256, 0, stream>>>(
        x, qkvw, projw, ts, kpm, Xb, Wq, Wp, tsw, tbf, qarr);

    gemm_bt<0, 4, 2><<<dim3(18, 32), 256, 0, stream>>>(Xb, Wq, qkvb, tsw, Qb, Kb, Vt, nullptr);

    attn_kernel<<<dim3(1024), 256, 0, stream>>>(Qb, Kb, Vt, tbf, Ob, qarr);

    kmerge_kernel<<<(2*2048*16) / 256, 256, 0, stream>>>(Kb, out + 3145728);

    gemm_bt<1, 2, 2><<<dim3(6, 64), 256, 0, stream>>>(Ob, Wp, projb, nullptr, nullptr, nullptr, nullptr, out);
}

// Round 21
// 103.850 us; speedup vs baseline: 1.3125x; 1.0860x over previous
//
#include <hip/hip_runtime.h>
#include <hip/hip_bf16.h>

typedef unsigned short u16;
typedef __bf16 bf16x8 __attribute__((ext_vector_type(8)));
typedef float f32x4 __attribute__((ext_vector_type(4)));

#define QSCALE (0.125f * 1.44269504088896340736f)   // hd^-0.5 * log2(e), folded into Q

__device__ __forceinline__ u16 f2bf(float f) {
    __hip_bfloat16 h = __float2bfloat16(f);
    return __builtin_bit_cast(u16, h);
}
__device__ __forceinline__ float bf2f(u16 u) {
    unsigned int x = ((unsigned int)u) << 16;
    return __builtin_bit_cast(float, x);
}
__device__ __forceinline__ bf16x8 ld_bf8(const u16* p) {
    uint4 u = *reinterpret_cast<const uint4*>(p);
    return __builtin_bit_cast(bf16x8, u);
}
__device__ __forceinline__ bf16x8 pack8f(f32x4 a, f32x4 b) {
    union { bf16x8 v; u16 u[8]; } r;
    #pragma unroll
    for (int i = 0; i < 4; i++) { r.u[i] = f2bf(a[i]); r.u[4+i] = f2bf(b[i]); }
    return r.v;
}
__device__ __forceinline__ bf16x8 pack8u(ushort4 a, ushort4 b) {
    union { bf16x8 v; ushort4 u[2]; } r;
    r.u[0] = a; r.u[1] = b;
    return r.v;
}

#define GLOAD_LDS16(g, l) __builtin_amdgcn_global_load_lds( \
    (const __attribute__((address_space(1))) unsigned int*)(g), \
    (__attribute__((address_space(3))) unsigned int*)(l), 16, 0, 0)

// counted vmcnt wait (T4): N = VMEM ops allowed to stay in flight
template<int N> __device__ __forceinline__ void s_wait_vmcnt() {
    if constexpr (N == 0)       asm volatile("s_waitcnt vmcnt(0)" ::: "memory");
    else if constexpr (N == 3)  asm volatile("s_waitcnt vmcnt(3)" ::: "memory");
    else if constexpr (N == 4)  asm volatile("s_waitcnt vmcnt(4)" ::: "memory");
    else if constexpr (N == 8)  asm volatile("s_waitcnt vmcnt(8)" ::: "memory");
}
__device__ __forceinline__ void s_bar() {
    __builtin_amdgcn_sched_barrier(0);
    __builtin_amdgcn_s_barrier();
    __builtin_amdgcn_sched_barrier(0);
}

// ---------------------------------------------------------------- prep ----
// f32->bf16 conversions; token-size weight tables (f32 for V-prescale,
// bf16 for the attn denominator fragment); zero the queue counter.
__global__ __launch_bounds__(256) void prep_kernel(
    const float* __restrict__ x, const float* __restrict__ qkvw,
    const float* __restrict__ projw, const float* __restrict__ ts,
    const unsigned char* __restrict__ kpm,
    u16* __restrict__ Xb, u16* __restrict__ Wq, u16* __restrict__ Wp,
    float* __restrict__ tsw, u16* __restrict__ tbf, int* __restrict__ qarr)
{
    int i = blockIdx.x * 256 + threadIdx.x;
    const int XC4 = 4096 * 768 / 4;
    const int WQ4 = 2304 * 768 / 4;
    const int WP4 = 768 * 768 / 4;
    const float* src = nullptr; u16* dst = nullptr;
    if (i < XC4) { src = x; dst = Xb; }
    else {
        i -= XC4;
        if (i < WQ4) { src = qkvw; dst = Wq; }
        else {
            i -= WQ4;
            if (i < WP4) { src = projw; dst = Wp; }
            else {
                i -= WP4;
                if (i < 1024) {
                    float4 t = *(const float4*)(ts + i*4);
                    uchar4 k = *(const uchar4*)(kpm + i*4);
                    float4 r;
                    r.x = k.x ? 0.f : fmaxf(t.x, 1e-8f);
                    r.y = k.y ? 0.f : fmaxf(t.y, 1e-8f);
                    r.z = k.z ? 0.f : fmaxf(t.z, 1e-8f);
                    r.w = k.w ? 0.f : fmaxf(t.w, 1e-8f);
                    *(float4*)(tsw + i*4) = r;
                    ushort4 o;
                    o.x = f2bf(r.x); o.y = f2bf(r.y);
                    o.z = f2bf(r.z); o.w = f2bf(r.w);
                    *(ushort4*)(tbf + i*4) = o;
                    return;
                }
                i -= 1024;
                if (i < 256) qarr[i] = 0;
                return;
            }
        }
    }
    float4 v = *(const float4*)(src + i*4);
    ushort4 o;
    o.x = f2bf(v.x); o.y = f2bf(v.y); o.z = f2bf(v.z); o.w = f2bf(v.w);
    *(ushort4*)(dst + i*4) = o;
}

// ---------------------------------------------------------------- GEMM ----
// C[m][n] = sum_k A[m][k]*Bm[n][k] (+bias). Tile = (MI*32) x 128, BK=32,
// 4 waves (2x2). 3-buffer, 1-ahead prefetch, ONE barrier + counted
// vmcnt(SA) per K-step (R13 configuration — session best).
template<int EPI, int MI>
__global__ __launch_bounds__(256, 2) void gemm_bt(
    const u16* __restrict__ A, const u16* __restrict__ Bm,
    const float* __restrict__ bias, const float* __restrict__ tsw,
    u16* __restrict__ Qb, u16* __restrict__ Kb, u16* __restrict__ Vt,
    float* __restrict__ outp)
{
    constexpr int BM = MI * 32;
    constexpr int ACALLS = MI / 2;
    constexpr int SA = ACALLS + 2;       // stage calls per wave per iter
    constexpr int NT = 24;
    __shared__ u16 As[3][BM * 32];
    __shared__ u16 Bs[3][128 * 32];
    const int K = 768;
    const int tid = threadIdx.x;
    const int nwg = gridDim.x * gridDim.y;
    const int flat = blockIdx.y * gridDim.x + blockIdx.x;
    const int per = nwg >> 3;
    const int swz = (flat & 7) * per + (flat >> 3);
    const int m0 = (swz / gridDim.x) * BM;
    const int n0 = (swz % gridDim.x) * 128;
    const int w = tid >> 6, lane = tid & 63;
    const int wr = (w >> 1) * (MI * 16), wc = (w & 1) * 64;
    const int g = lane >> 4, l16 = lane & 15;

    const int srow = lane >> 2;
    const int scol = (lane & 3) * 8;
    const u16* gA[ACALLS];
    #pragma unroll
    for (int c = 0; c < ACALLS; c++)
        gA[c] = A + (size_t)(m0 + (c*4 + w)*16 + srow) * K + scol;
    const u16* gB[2];
    #pragma unroll
    for (int c = 0; c < 2; c++)
        gB[c] = Bm + (size_t)(n0 + (c*4 + w)*16 + srow) * K + scol;

#define GSTAGE(buf, kk) do { \
    _Pragma("unroll") \
    for (int c = 0; c < ACALLS; c++) \
        GLOAD_LDS16(gA[c] + (kk), &As[buf][(c*4 + w) * 512]); \
    _Pragma("unroll") \
    for (int c = 0; c < 2; c++) \
        GLOAD_LDS16(gB[c] + (kk), &Bs[buf][(c*4 + w) * 512]); } while (0)

    f32x4 acc[MI][4] = {};
    GSTAGE(0, 0);
    int cur = 0;
    for (int it = 0; it < NT; it++) {
        const int k0 = it * 32;
        const int nxt = (cur == 2) ? 0 : cur + 1;
        if (it + 1 < NT) {
            GSTAGE(nxt, k0 + 32);
            s_wait_vmcnt<SA>();          // stage(it) done; stage(it+1) flies on
        } else {
            s_wait_vmcnt<0>();
        }
        s_bar();                         // buf[cur] present for all waves
        bf16x8 af[MI], bfr[4];
        #pragma unroll
        for (int i = 0; i < MI; i++) af[i]  = ld_bf8(&As[cur][(wr + i*16 + l16)*32 + g*8]);
        #pragma unroll
        for (int j = 0; j < 4; j++)  bfr[j] = ld_bf8(&Bs[cur][(wc + j*16 + l16)*32 + g*8]);
        #pragma unroll
        for (int i = 0; i < MI; i++)
            #pragma unroll
            for (int j = 0; j < 4; j++)
                acc[i][j] = __builtin_amdgcn_mfma_f32_16x16x32_bf16(af[i], bfr[j], acc[i][j], 0, 0, 0);
        cur = nxt;
        // no second barrier: buf reuse distance = 2 barriers (safe)
    }
#undef GSTAGE

    #pragma unroll
    for (int j = 0; j < 4; j++) {
        const int n = n0 + wc + j*16 + l16;
        const float bs = bias[n];
        #pragma unroll
        for (int i = 0; i < MI; i++) {
            #pragma unroll
            for (int r = 0; r < 4; r++) {
                const int m = m0 + wr + i*16 + g*4 + r;
                float v = acc[i][j][r] + bs;
                if (EPI == 0) {
                    int b = m >> 11, l = m & 2047;
                    unsigned int which = (unsigned int)n / 768u;
                    int rem = n - (int)which * 768;
                    int h = rem >> 6, d = rem & 63;
                    int bh = b * 12 + h;
                    if (which == 0)      Qb[((size_t)bh*2048 + l)*64 + d] = f2bf(v * QSCALE);
                    else if (which == 1) Kb[((size_t)bh*2048 + l)*64 + d] = f2bf(v);
                    else                 Vt[((size_t)bh*64 + d)*2048 + l] = f2bf(v * tsw[b*2048 + l]);
                } else {
                    outp[(size_t)m * 768 + n] = v;
                }
            }
        }
    }
}

// ----------------------------------------------------------- attention ----
// Persistent-block flash attention, swapped-operand form. 3-buffer staging,
// ONE barrier per kt iteration, counted vmcnt. Dynamic largest-first queue.
// Grid 512 (R13 configuration — session best).
__global__ __launch_bounds__(256, 2) void attn_kernel(
    const u16* __restrict__ Q, const u16* __restrict__ Kb,
    const u16* __restrict__ Vt, const u16* __restrict__ tbf,
    u16* __restrict__ O, int* __restrict__ qarr)
{
    __shared__ u16 Ks[3][64 * 64];
    __shared__ u16 Vs[3][64 * 64];
    __shared__ int s_item;
    const int tid = threadIdx.x;
    const int w = tid >> 6, lane = tid & 63;
    const int g = lane >> 4, l16 = lane & 15;
    const int sw = l16 & 7;
    const int srow = lane >> 3;
    const int sslot = (lane & 7) ^ srow;

    for (;;) {
        __syncthreads();                            // s_item rewrite guard
        if (tid == 0) {
            const int i = atomicAdd(&qarr[0], 1);
            s_item = (i < 768) ? i : -1;
        }
        __syncthreads();
        const int item = s_item;
        if (item < 0) return;
        const int qt = 31 - (item / 24);            // largest work first
        const int bh = item - (item / 24) * 24;
        const int b = bh / 12, h = bh - b * 12;
        const int q0 = qt * 64 + w * 16;            // this wave's 16 q-rows
        const int nkt = qt + 1;

        const u16* Qp = Q + ((size_t)bh * 2048 + q0) * 64;
        const u16* Kp = Kb + (size_t)bh * 2048 * 64;
        const u16* Vp = Vt + (size_t)bh * 64 * 2048;
        const u16* tb = tbf + b * 2048;

        const u16* gK0 = Kp + (size_t)(w*16 +     srow) * 64   + sslot * 8;
        const u16* gK1 = Kp + (size_t)(w*16 + 8 + srow) * 64   + sslot * 8;
        const u16* gV0 = Vp + (size_t)(w*16 +     srow) * 2048 + sslot * 8;
        const u16* gV1 = Vp + (size_t)(w*16 + 8 + srow) * 2048 + sslot * 8;

#define ASTAGE(buf, kk) do { \
    GLOAD_LDS16(gK0 + (size_t)(kk) * 64, &Ks[buf][(w*16    ) * 64]); \
    GLOAD_LDS16(gK1 + (size_t)(kk) * 64, &Ks[buf][(w*16 + 8) * 64]); \
    GLOAD_LDS16(gV0 + (kk),              &Vs[buf][(w*16    ) * 64]); \
    GLOAD_LDS16(gV1 + (kk),              &Vs[buf][(w*16 + 8) * 64]); } while (0)

        const bf16x8 qf0 = ld_bf8(Qp + l16 * 64 + g * 8);
        const bf16x8 qf1 = ld_bf8(Qp + l16 * 64 + 32 + g * 8);

        // prologue: t(0) fragment + stage(0)
        ushort4 tc0, tc1, tc2, tc3;
        { const u16* tp = tb + 4*g;
          tc0 = *(const ushort4*)(tp);      tc1 = *(const ushort4*)(tp + 16);
          tc2 = *(const ushort4*)(tp + 32); tc3 = *(const ushort4*)(tp + 48); }
        ASTAGE(0, 0);

        f32x4 o[4] = {};
        f32x4 lpacc = {};
        float m = -1e30f;
        const int qmy = q0 + l16;                   // q-row this lane reduces

        int cur = 0;
        for (int kt = 0; kt < nkt; kt++) {
            const int k0 = kt * 64;
            const int nxt = (cur == 2) ? 0 : cur + 1;

            ushort4 tn0 = tc0, tn1 = tc1, tn2 = tc2, tn3 = tc3;
            if (kt + 1 < nkt) {                     // block-uniform
                const u16* tp = tb + k0 + 64 + 4*g;
                tn0 = *(const ushort4*)(tp);      tn1 = *(const ushort4*)(tp + 16);
                tn2 = *(const ushort4*)(tp + 32); tn3 = *(const ushort4*)(tp + 48);
                ASTAGE(nxt, k0 + 64);
                s_wait_vmcnt<8>();                  // stage(kt) done; 8 newest fly on
            } else {
                s_wait_vmcnt<0>();
            }
            s_bar();                                // buf[cur] present for all waves

            // ---- batch-issue ALL LDS reads (8 K b128 + 16 V b64) ----
            const int ko0 = 8 * (g ^ sw);
            bf16x8 kf[4][2];
            #pragma unroll
            for (int t = 0; t < 4; t++) {
                const u16* kb = &Ks[cur][(t*16 + l16) * 64];
                kf[t][0] = ld_bf8(kb + ko0);
                kf[t][1] = ld_bf8(kb + (ko0 ^ 32));
            }
            const int gh = g >> 1, gl = 4 * (g & 1);
            ushort4 va[4][4];
            #pragma unroll
            for (int j = 0; j < 4; j++) {
                const u16* vb = &Vs[cur][(j*16 + l16) * 64];
                va[j][0] = *(const ushort4*)(vb + (((0 + gh) ^ sw) << 3) + gl);
                va[j][1] = *(const ushort4*)(vb + (((2 + gh) ^ sw) << 3) + gl);
                va[j][2] = *(const ushort4*)(vb + (((4 + gh) ^ sw) << 3) + gl);
                va[j][3] = *(const ushort4*)(vb + (((6 + gh) ^ sw) << 3) + gl);
            }

            // ---- S^T = K · Q^T ----
            f32x4 s[4];
            #pragma unroll
            for (int t = 0; t < 4; t++) {
                f32x4 z = {};
                z = __builtin_amdgcn_mfma_f32_16x16x32_bf16(kf[t][0], qf0, z, 0, 0, 0);
                z = __builtin_amdgcn_mfma_f32_16x16x32_bf16(kf[t][1], qf1, z, 0, 0, 0);
                s[t] = z;
            }
            // ---- causal mask only on the diagonal tile (block-uniform) ----
            if (kt == qt) {
                #pragma unroll
                for (int t = 0; t < 4; t++)
                    #pragma unroll
                    for (int r = 0; r < 4; r++) {
                        const int key = k0 + t*16 + 4*g + r;
                        if (key > qmy) s[t][r] = -1e30f;
                    }
            }
            // ---- per-q max ----
            float pmax = -1e30f;
            #pragma unroll
            for (int t = 0; t < 4; t++)
                #pragma unroll
                for (int r = 0; r < 4; r++)
                    pmax = fmaxf(pmax, s[t][r]);
            pmax = fmaxf(pmax, __shfl_xor(pmax, 16));
            pmax = fmaxf(pmax, __shfl_xor(pmax, 32));
            // ---- online update, defer-max (THR=8, log2 domain) ----
            if (!__all(pmax <= m + 8.f)) {
                const float mn = fmaxf(m, pmax);
                const float sc = __builtin_amdgcn_exp2f(m - mn);
                m = mn;
                #pragma unroll
                for (int r = 0; r < 4; r++) {
                    const float scr = __shfl(sc, (lane & 48) + 4*g + r);
                    o[0][r] *= scr; o[1][r] *= scr; o[2][r] *= scr; o[3][r] *= scr;
                    lpacc[r] *= scr;
                }
            }
            // ---- P = exp2(s - m) ----
            #pragma unroll
            for (int t = 0; t < 4; t++)
                #pragma unroll
                for (int r = 0; r < 4; r++)
                    s[t][r] = __builtin_amdgcn_exp2f(s[t][r] - m);
            const bf16x8 pa01 = pack8f(s[0], s[1]);
            const bf16x8 pa23 = pack8f(s[2], s[3]);
            __builtin_amdgcn_s_setprio(1);
            // ---- denominator: Σ p·t via MFMA with t-fragment B ----
            lpacc = __builtin_amdgcn_mfma_f32_16x16x32_bf16(pa01, pack8u(tc0, tc1), lpacc, 0, 0, 0);
            lpacc = __builtin_amdgcn_mfma_f32_16x16x32_bf16(pa23, pack8u(tc2, tc3), lpacc, 0, 0, 0);
            // ---- O += P·V' (V prescaled by t; key-perm cancels A vs B) ----
            #pragma unroll
            for (int j = 0; j < 4; j++) {
                o[j] = __builtin_amdgcn_mfma_f32_16x16x32_bf16(pa01, pack8u(va[j][0], va[j][1]), o[j], 0, 0, 0);
                o[j] = __builtin_amdgcn_mfma_f32_16x16x32_bf16(pa23, pack8u(va[j][2], va[j][3]), o[j], 0, 0, 0);
            }
            __builtin_amdgcn_s_setprio(0);
            tc0 = tn0; tc1 = tn1; tc2 = tn2; tc3 = tn3;
            cur = nxt;
            // no end-of-iter barrier: buffer reuse distance = 3 iterations
        }
#undef ASTAGE

        // ---- normalize + write (lpacc[r] = Σ p·t for q-row 4g+r) ----
        float rlr[4];
        #pragma unroll
        for (int r = 0; r < 4; r++) rlr[r] = 1.f / lpacc[r];
        #pragma unroll
        for (int j = 0; j < 4; j++)
            #pragma unroll
            for (int r = 0; r < 4; r++) {
                const int q = q0 + 4*g + r;
                O[((size_t)b*2048 + q)*768 + h*64 + j*16 + l16] = f2bf(o[j][r] * rlr[r]);
            }
    }
}

// ------------------------------------------------------------- k_merge ----
__global__ __launch_bounds__(256) void kmerge_kernel(
    const u16* __restrict__ Kb, float* __restrict__ out)
{
    const int idx = blockIdx.x * 256 + threadIdx.x;   // < 2*2048*16
    const int d4 = (idx & 15) * 4;
    const int l = (idx >> 4) & 2047;
    const int b = idx >> 15;
    float4 acc = {0.f, 0.f, 0.f, 0.f};
    #pragma unroll
    for (int h = 0; h < 12; h++) {
        ushort4 v = *(const ushort4*)&Kb[(((size_t)(b*12 + h))*2048 + l)*64 + d4];
        acc.x += bf2f(v.x); acc.y += bf2f(v.y);
        acc.z += bf2f(v.z); acc.w += bf2f(v.w);
    }
    const float s = 1.f / 12.f;
    float4 r = {acc.x * s, acc.y * s, acc.z * s, acc.w * s};
    *(float4*)&out[(((size_t)b*2048 + l))*64 + d4] = r;
}

// -------------------------------------------------------------- launch ----
extern "C" void kernel_launch(void* const* d_in, const int* in_sizes, int n_in,
                              void* d_out, int out_size, void* d_ws, size_t ws_size,
                              hipStream_t stream)
{
    const float* x     = (const float*)d_in[0];
    const float* ts    = (const float*)d_in[1];
    // d_in[2] = attn_mask (causal, hardcoded)
    const unsigned char* kpm = (const unsigned char*)d_in[3];
    const float* qkvw  = (const float*)d_in[4];
    const float* qkvb  = (const float*)d_in[5];
    const float* projw = (const float*)d_in[6];
    const float* projb = (const float*)d_in[7];
    float* out = (float*)d_out;

    char* ws = (char*)d_ws;
    u16* Xb = (u16*)ws;  ws += (size_t)4096 * 768 * 2;
    u16* Wq = (u16*)ws;  ws += (size_t)2304 * 768 * 2;
    u16* Wp = (u16*)ws;  ws += (size_t)768 * 768 * 2;
    u16* Qb = (u16*)ws;  ws += (size_t)24 * 2048 * 64 * 2;
    u16* Kb = (u16*)ws;  ws += (size_t)24 * 2048 * 64 * 2;
    u16* Vt = (u16*)ws;  ws += (size_t)24 * 2048 * 64 * 2;
    u16* Ob = (u16*)ws;  ws += (size_t)4096 * 768 * 2;
    float* tsw = (float*)ws;  ws += (size_t)2 * 2048 * 4;
    u16* tbf = (u16*)ws;  ws += (size_t)2 * 2048 * 2;
    int* qarr = (int*)ws;

    const int prep4 = (4096*768 + 2304*768 + 768*768) / 4 + 1024 + 256;
    prep_kernel<<<(prep4 + 255) / 256, 256, 0, stream>>>(
        x, qkvw, projw, ts, kpm, Xb, Wq, Wp, tsw, tbf, qarr);

    gemm_bt<0, 4><<<dim3(18, 32), 256, 0, stream>>>(Xb, Wq, qkvb, tsw, Qb, Kb, Vt, nullptr);

    attn_kernel<<<dim3(512), 256, 0, stream>>>(Qb, Kb, Vt, tbf, Ob, qarr);

    kmerge_kernel<<<(2*2048*16) / 256, 256, 0, stream>>>(Kb, out + 3145728);

    gemm_bt<1, 2><<<dim3(6, 64), 256, 0, stream>>>(Ob, Wp, projb, nullptr, nullptr, nullptr, nullptr, out);
}